// Round 1
// baseline (701.384 us; speedup 1.0000x reference)
//
#include <hip/hip_runtime.h>

// MessageFunction: out[b,m,n] = sum_e W_e[m,e]*e_vw[b,e,n]
//                             + sum_f W_h[m,f]*h_w[b,f,n] + b_e[m] + b_h[m]
// B=1024, E=NODE=128 (K=256 fused), M=128, N=512. Memory-bound batched GEMM.
// Strategy: bf16 MFMA 16x16x32, W resident in registers (per-wave 32 rows),
// X streamed through LDS with a free transpose (column-per-lane loads).

typedef __bf16 bf16x8 __attribute__((ext_vector_type(8)));
typedef float  f32x4  __attribute__((ext_vector_type(4)));

#define NDIM   512
#define MDIM   128
#define NCHUNK 64
#define KLD    264   // padded LDS k-stride (bf16 elems); 264*2B = 33 dwords*16B

__global__ __launch_bounds__(256) void msg_kernel(
    const float* __restrict__ h_w,
    const float* __restrict__ e_vw,
    const float* __restrict__ W_e,
    const float* __restrict__ b_e,
    const float* __restrict__ W_h,
    const float* __restrict__ b_h,
    float* __restrict__ out)
{
  __shared__ __align__(16) __bf16 Xs[NCHUNK][KLD];   // Xs[n][k], 33 KB

  const int b    = blockIdx.x;
  const int tid  = threadIdx.x;
  const int lane = tid & 63;
  const int wave = tid >> 6;
  const int l15  = lane & 15;
  const int quad = lane >> 4;
  const int mbase = wave * 32;      // wave owns W rows [mbase, mbase+32)

  // ---- Resident A fragments (bf16): A[m = l15][k = quad*8 + j] per 16x16x32 tile
  bf16x8 afrag[2][8];
#pragma unroll
  for (int mt = 0; mt < 2; ++mt) {
    const int m = mbase + mt * 16 + l15;
#pragma unroll
    for (int ks = 0; ks < 8; ++ks) {
      const int k0 = ks * 32 + quad * 8;          // 0..248, runs of 8 never cross 128
      const float* src = (k0 < 128) ? (W_e + m * 128 + k0)
                                    : (W_h + m * 128 + (k0 - 128));
      f32x4 lo = *(const f32x4*)(src);
      f32x4 hi = *(const f32x4*)(src + 4);
      bf16x8 f;
      f[0] = (__bf16)lo[0]; f[1] = (__bf16)lo[1];
      f[2] = (__bf16)lo[2]; f[3] = (__bf16)lo[3];
      f[4] = (__bf16)hi[0]; f[5] = (__bf16)hi[1];
      f[6] = (__bf16)hi[2]; f[7] = (__bf16)hi[3];
      afrag[mt][ks] = f;
    }
  }

  // ---- Per-lane bias for the rows this lane stores (D row = quad*4 + r)
  float bias[2][4];
#pragma unroll
  for (int mt = 0; mt < 2; ++mt)
#pragma unroll
    for (int r = 0; r < 4; ++r) {
      const int m = mbase + mt * 16 + quad * 4 + r;
      bias[mt][r] = b_e[m] + b_h[m];
    }

  // ---- Staging source: wave w stages k-rows [64w, 64w+64) of X = [e_vw; h_w]
  const int krow0 = wave * 64;
  const float* src_base = (wave < 2)
      ? (e_vw + ((size_t)b * 128 + krow0) * NDIM)
      : (h_w  + ((size_t)b * 128 + (krow0 - 128)) * NDIM);

  float* outb = out + (size_t)b * MDIM * NDIM;
  const f32x4 fzero = {0.f, 0.f, 0.f, 0.f};

  for (int c = 0; c < 8; ++c) {
    const int n0 = c * NCHUNK;

    // ---- Stage X chunk into LDS, transposed to [n][k], cvt fp32->bf16.
    // Lane owns column n0+lane: each of the 8 loads per group is a fully
    // coalesced wave-wide dword read; write is one ds_write_b128.
#pragma unroll 2
    for (int g = 0; g < 8; ++g) {
      const float* p = src_base + (size_t)(g * 8) * NDIM + n0 + lane;
      float t[8];
#pragma unroll
      for (int j = 0; j < 8; ++j) t[j] = p[(size_t)j * NDIM];
      bf16x8 v;
#pragma unroll
      for (int j = 0; j < 8; ++j) v[j] = (__bf16)t[j];
      *(bf16x8*)&Xs[lane][krow0 + g * 8] = v;
    }
    __syncthreads();

    f32x4 acc[2][4];
#pragma unroll
    for (int mt = 0; mt < 2; ++mt)
#pragma unroll
      for (int nt = 0; nt < 4; ++nt)
        acc[mt][nt] = fzero;

#pragma unroll
    for (int ks = 0; ks < 8; ++ks) {
      bf16x8 bfrag[4];   // B[k = quad*8 + j][n = l15] -> one ds_read_b128 each
#pragma unroll
      for (int nt = 0; nt < 4; ++nt)
        bfrag[nt] = *(const bf16x8*)&Xs[nt * 16 + l15][ks * 32 + quad * 8];
#pragma unroll
      for (int mt = 0; mt < 2; ++mt)
#pragma unroll
        for (int nt = 0; nt < 4; ++nt)
          acc[mt][nt] = __builtin_amdgcn_mfma_f32_16x16x32_bf16(
              afrag[mt][ks], bfrag[nt], acc[mt][nt], 0, 0, 0);
    }

    // ---- Epilogue: D col = l15, row = quad*4 + r
#pragma unroll
    for (int mt = 0; mt < 2; ++mt)
#pragma unroll
      for (int nt = 0; nt < 4; ++nt)
#pragma unroll
        for (int r = 0; r < 4; ++r) {
          const int m = mbase + mt * 16 + quad * 4 + r;
          outb[(size_t)m * NDIM + n0 + nt * 16 + l15] = acc[mt][nt][r] + bias[mt][r];
        }
    __syncthreads();   // guard Xs overwrite by next chunk's staging
  }
}

extern "C" void kernel_launch(void* const* d_in, const int* in_sizes, int n_in,
                              void* d_out, int out_size, void* d_ws, size_t ws_size,
                              hipStream_t stream) {
  // setup_inputs order: h_v(unused), h_w, e_vw, W_e, b_e, W_h, b_h
  const float* h_w  = (const float*)d_in[1];
  const float* e_vw = (const float*)d_in[2];
  const float* W_e  = (const float*)d_in[3];
  const float* b_e  = (const float*)d_in[4];
  const float* W_h  = (const float*)d_in[5];
  const float* b_h  = (const float*)d_in[6];
  float* out = (float*)d_out;

  msg_kernel<<<dim3(1024), dim3(256), 0, stream>>>(h_w, e_vw, W_e, b_e, W_h, b_h, out);
}